// Round 1
// 157.494 us; speedup vs baseline: 1.0986x; 1.0986x over previous
//
#include <hip/hip_runtime.h>
#include <cstddef>
#include <cstdint>

// z: (8, 256, 16,16,16) fp32; embedding: (1024, 256) fp32
#define CDIM 256
#define SPAT 4096
#define KCODE 1024

#define LOSS_OFF 8388608
#define PERP_OFF 8388609
#define IDX_OFF  8388610

typedef __bf16 bf16x8 __attribute__((ext_vector_type(8)));
typedef float floatx16 __attribute__((ext_vector_type(16)));
typedef unsigned short ushort8 __attribute__((ext_vector_type(8)));

__device__ __forceinline__ unsigned short f2bf_rne(float f) {
    union { float f; uint32_t u; } c; c.f = f;
    uint32_t u = c.u;
    return (unsigned short)((u + 0x7fffu + ((u >> 16) & 1u)) >> 16);
}
__device__ __forceinline__ float bf2f(unsigned short h) {
    union { float f; uint32_t u; } c; c.u = ((uint32_t)h) << 16;
    return c.f;
}

// async global->LDS, 16B per lane; lds dest = uniform base + lane*16
__device__ __forceinline__ void dma16(const void* g, void* l) {
    __builtin_amdgcn_global_load_lds(
        (const __attribute__((address_space(1))) void*)g,
        (__attribute__((address_space(3))) void*)l, 16, 0, 0);
}

// ---------------------------------------------------------------------------
// Prep: split embedding into bf16 hi/lo in the bank-swizzled stage layout:
//   ushort index = stage*8192 + ks*256 + phys*8 + (c&7)
//   phys = kb ^ (ks & 7),  kb = c>>3 (0..31), ks = code&31, stage = code>>5
// Also enorm (exact R1 reduction order) and zero counts/losssum. UNCHANGED.
// ---------------------------------------------------------------------------
__global__ __launch_bounds__(256) void vq_prep(const float* __restrict__ emb,
                                               unsigned short* __restrict__ ehsw,
                                               unsigned short* __restrict__ elsw,
                                               float* __restrict__ enorm,
                                               float* __restrict__ counts,
                                               float* __restrict__ losssum) {
    int tid = threadIdx.x;
    if (blockIdx.x == 0) {
        for (int i = tid; i < KCODE; i += 256) counts[i] = 0.0f;
        if (tid == 0) losssum[0] = 0.0f;
    }
    int w = tid >> 6, lane = tid & 63;
    int k = blockIdx.x * 4 + w;
    const float* row = emb + (size_t)k * CDIM;
    float s = 0.0f;
#pragma unroll
    for (int i = 0; i < 4; ++i) {
        float v = row[lane + 64 * i];
        s = fmaf(v, v, s);
    }
#pragma unroll
    for (int m = 32; m > 0; m >>= 1) s += __shfl_xor(s, m, 64);
    if (lane == 0) enorm[k] = s;

    float4 v4 = *(const float4*)(row + lane * 4);
    unsigned short h0 = f2bf_rne(v4.x), h1 = f2bf_rne(v4.y),
                   h2 = f2bf_rne(v4.z), h3 = f2bf_rne(v4.w);
    ushort4 hv = make_ushort4(h0, h1, h2, h3);
    ushort4 lv = make_ushort4(f2bf_rne(v4.x - bf2f(h0)), f2bf_rne(v4.y - bf2f(h1)),
                              f2bf_rne(v4.z - bf2f(h2)), f2bf_rne(v4.w - bf2f(h3)));
    int kb = lane >> 1, cj = (lane & 1) * 4;
    int st = k >> 5, ks = k & 31;
    int phys = kb ^ (ks & 7);
    size_t dst = (size_t)st * 8192 + ks * 256 + phys * 8 + cj;
    *(ushort4*)(ehsw + dst) = hv;
    *(ushort4*)(elsw + dst) = lv;
}

// ---------------------------------------------------------------------------
// Main: bf16x3 MFMA distance GEMM + split-K argmin + gather + loss + counts
// NOW 256 blocks x 512 threads (8 waves) -> 2 waves/SIMD for latency hiding.
// Wave w: kh = w>>2 (code half), cq = w&3 (32-col quarter: cols cq*32..+32).
// Each wave: ONE 32x32 accumulator, frags zh/zl[16] = 128 VGPR (fits 2/SIMD).
// MFMA chain order per acc (aeh*bh, ael*bh, aeh*bl) identical to R1 -> idx
// bit-exact. DMA: wave w loads buffer (w>>1) half (w&1): 8x dma16/stage.
// Gather phase: 128 selected rows DMA'd into LDS (slot-interleaved, 1040B
// stride, ~4-way banks) -> kills 32K scattered L2 scalar loads per block;
// loss loop runs on tid<256 with the EXACT old mapping (bitwise loss).
// ---------------------------------------------------------------------------
__global__ __launch_bounds__(512, 2) void vq_main(const float* __restrict__ z,
                                                  const float* __restrict__ emb,
                                                  const unsigned short* __restrict__ ehsw,
                                                  const unsigned short* __restrict__ elsw,
                                                  const float* __restrict__ enorm,
                                                  float* __restrict__ counts,
                                                  float* __restrict__ losssum,
                                                  float* __restrict__ out) {
    __shared__ __align__(16) unsigned char lds[131072 + 4096 + 512 + 1024 + 1024 + 512];
    float* zhalf = (float*)lds;                       // phase1 overlay on buf0
    float* ens_s = (float*)(lds + 131072);            // 1024 f
    float* zzs   = (float*)(lds + 135168);            // 128 f
    float* pb_s  = (float*)(lds + 135680);            // [2][128]
    int*   pb_i  = (int*)(lds + 136704);              // [2][128]
    int*   bidxs = (int*)(lds + 137728);              // 128 i

    const int tid = threadIdx.x;
    const int w = tid >> 6;            // wave id 0..7
    const int lane = tid & 63;
    const int m_ = lane & 31;
    const int g = lane >> 5;
    const int kh = w >> 2;             // code-pair (0: codes 0..511, 1: 512..1023)
    const int cq = w & 3;              // column quarter (cols cq*32 .. +32)
    const int ch = cq & 1;             // 32-col offset within the 64-col half
    const int hlf = cq >> 1;           // which 64-col half this wave extracts
    const int n0 = blockIdx.x * 128;
    const int b = n0 >> 12;
    const int sp0 = n0 & 4095;
    const float* zb = z + (size_t)b * CDIM * SPAT + sp0;

    ushort8 zh[16], zl[16];

    // ---- phase 1: two 64-col halves ----
    for (int h = 0; h < 2; ++h) {
        for (int i = tid; i < CDIM * 16; i += 512) {
            int c = i >> 4, seg = i & 15;
            *(float4*)&zhalf[c * 64 + seg * 4] =
                *(const float4*)(zb + (size_t)c * SPAT + h * 64 + seg * 4);
        }
        __syncthreads();
        if (hlf == h) {
            // 4 waves extract this half; each takes its 32-col quarter
#pragma unroll
            for (int kc = 0; kc < 16; ++kc) {
#pragma unroll
                for (int j = 0; j < 8; ++j) {
                    float v = zhalf[(kc * 16 + g * 8 + j) * 64 + ch * 32 + m_];
                    unsigned short hb = f2bf_rne(v);
                    unsigned short lb = f2bf_rne(v - bf2f(hb));
                    zh[kc][j] = hb; zl[kc][j] = lb;
                }
            }
        } else if (w == (h == 0 ? 2 : 0)) {
            // zz per column (R1-exact sequential fmaf order), one free wave
            float s = 0.0f;
            for (int c = 0; c < CDIM; ++c) {
                float v = zhalf[c * 64 + lane];
                s = fmaf(v, v, s);
            }
            zzs[h * 64 + lane] = s;
        } else if (h == 0 && w == 3) {
            for (int i = lane; i < KCODE; i += 64) ens_s[i] = enorm[i];
        }
        __syncthreads();
    }

    const float zzv = zzs[cq * 32 + m_];

    float bs = 3.4e38f;
    int bi_ = 0;

    // wave's DMA role: buffer (w>>1) in {eh0, el0, eh1, el1}, half (w&1)
    const int bufid = w >> 1;
    const int hf = w & 1;
    const char* gsrc = (const char*)((bufid & 1) ? elsw : ehsw);
    const int gs0 = kh * 16;           // global stage base for this code-pair

    // ---- stage-0 DMA prologue ----
    {
        const char* gp = gsrc + ((size_t)gs0 << 14) + (hf << 13) + (lane << 4);
        char* lp = (char*)lds + ((size_t)bufid << 14) + (hf << 13);
#pragma unroll
        for (int j = 0; j < 8; ++j) dma16(gp + j * 1024, lp + j * 1024);
    }

    // ---- main loop: 16 stages, double-buffered ----
    for (int s = 0; s < 16; ++s) {
        __syncthreads();   // drains DMA(s); all waves done with buf[(s+1)&1]
        if (s < 15) {
            const char* gp = gsrc + ((size_t)(gs0 + s + 1) << 14) + (hf << 13) + (lane << 4);
            char* lp = (char*)lds + (((size_t)(s + 1) & 1) << 16) +
                       ((size_t)bufid << 14) + (hf << 13);
#pragma unroll
            for (int j = 0; j < 8; ++j) dma16(gp + j * 1024, lp + j * 1024);
            __builtin_amdgcn_sched_barrier(0);   // keep DMA issue above compute
        }
        const char* EHb = (const char*)lds + (((size_t)s & 1) << 16) + ((size_t)kh << 15);
        const char* ELb = EHb + 16384;

        floatx16 a = {0.0f, 0.0f, 0.0f, 0.0f, 0.0f, 0.0f, 0.0f, 0.0f,
                      0.0f, 0.0f, 0.0f, 0.0f, 0.0f, 0.0f, 0.0f, 0.0f};
#pragma unroll
        for (int kc = 0; kc < 16; ++kc) {
            int kb0 = kc * 2 + g;
            int off = m_ * 512 + ((kb0 ^ (m_ & 7)) << 4);
            bf16x8 aeh = *(const bf16x8*)(EHb + off);
            bf16x8 ael = *(const bf16x8*)(ELb + off);
            bf16x8 bh = __builtin_bit_cast(bf16x8, zh[kc]);
            bf16x8 bl = __builtin_bit_cast(bf16x8, zl[kc]);
            a = __builtin_amdgcn_mfma_f32_32x32x16_bf16(aeh, bh, a, 0, 0, 0);
            a = __builtin_amdgcn_mfma_f32_32x32x16_bf16(ael, bh, a, 0, 0, 0);
            a = __builtin_amdgcn_mfma_f32_32x32x16_bf16(aeh, bl, a, 0, 0, 0);
        }

        // epilogue: ascending code order per lane; strict < keeps lowest idx
#pragma unroll
        for (int reg = 0; reg < 16; ++reg) {
            int mm = (reg & 3) + 8 * (reg >> 2) + 4 * g;
            int code = kh * 512 + s * 32 + mm;
            float en = ens_s[code];
            float d = (zzv + en) - 2.0f * a[reg];
            if (d < bs) { bs = d; bi_ = code; }
        }
    }

    // ---- merge g-halves (disjoint code subsets), tie -> low index ----
    {
        float s2 = __shfl_xor(bs, 32, 64);
        int i2 = __shfl_xor(bi_, 32, 64);
        if (s2 < bs || (s2 == bs && i2 < bi_)) { bs = s2; bi_ = i2; }
    }
    __syncthreads();        // everyone done with stage buffers / ens reads
    if (lane < 32) {
        pb_s[kh * 128 + cq * 32 + m_] = bs;
        pb_i[kh * 128 + cq * 32 + m_] = bi_;
    }
    __syncthreads();
    if (tid < 128) {
        float s0 = pb_s[tid], s1 = pb_s[128 + tid];
        int i0 = pb_i[tid], i1 = pb_i[128 + tid];
        // pair-0 indices always lower: tie keeps pair 0
        int ki = (s1 < s0) ? i1 : i0;
        bidxs[tid] = ki;
        out[IDX_OFF + n0 + tid] = (float)ki;
        atomicAdd(&counts[ki], 1.0f);
    }
    __syncthreads();

    // ---- DMA the 128 selected embedding rows into LDS ----
    // slot(row) = (row&3)*32 + (row>>2); byte offset slot*1040 (16B aligned).
    // Gather read bank = (4*col4 + c) % 32 -> ~4-way (cheap).
#pragma unroll
    for (int r = 0; r < 16; ++r) {
        int row = w * 16 + r;
        int k = bidxs[row];
        int slot = (row & 3) * 32 + (row >> 2);
        dma16((const char*)emb + ((size_t)k << 10) + (lane << 4),
              (char*)lds + (size_t)slot * 1040);
    }
    __syncthreads();

    // ---- gather z_q, STE output zp + (q - zp), loss ----
    // EXACT old 256-thread mapping preserved (bitwise loss); waves 4-7 retire.
    if (tid < 256) {
        float ls = 0.0f;
        float* outz = out + (size_t)b * CDIM * SPAT + sp0;
        const int col4 = tid & 31;         // this thread's 4 columns
        const int c_0 = tid >> 5;          // starting c, stride 8
        const float* e0 = (const float*)((const char*)lds + (size_t)(0 * 32 + col4) * 1040);
        const float* e1 = (const float*)((const char*)lds + (size_t)(1 * 32 + col4) * 1040);
        const float* e2 = (const float*)((const char*)lds + (size_t)(2 * 32 + col4) * 1040);
        const float* e3 = (const float*)((const char*)lds + (size_t)(3 * 32 + col4) * 1040);
        for (int c = c_0; c < CDIM; c += 8) {
            float4 zp = *(const float4*)(zb + (size_t)c * SPAT + col4 * 4);
            float d0 = e0[c] - zp.x, d1 = e1[c] - zp.y,
                  d2 = e2[c] - zp.z, d3 = e3[c] - zp.w;
            float4 o;
            o.x = zp.x + d0; o.y = zp.y + d1; o.z = zp.z + d2; o.w = zp.w + d3;
            ls = fmaf(d0, d0, ls); ls = fmaf(d1, d1, ls);
            ls = fmaf(d2, d2, ls); ls = fmaf(d3, d3, ls);
            *(float4*)(outz + (size_t)c * SPAT + col4 * 4) = o;
        }
#pragma unroll
        for (int m = 32; m > 0; m >>= 1) ls += __shfl_xor(ls, m, 64);
        if (lane == 0) atomicAdd(losssum, ls);
    }
}

// ---------------------------------------------------------------------------
// loss + perplexity
// ---------------------------------------------------------------------------
__global__ __launch_bounds__(256) void vq_finalize(const float* __restrict__ counts,
                                                   const float* __restrict__ losssum,
                                                   float* __restrict__ out) {
    __shared__ float red[256];
    int tid = threadIdx.x;
    float s = 0.0f;
    for (int k = tid; k < KCODE; k += 256) {
        float em = counts[k] * (1.0f / 32768.0f);
        s += em * logf(em + 1e-10f);
    }
    red[tid] = s;
    __syncthreads();
    for (int off = 128; off > 0; off >>= 1) {
        if (tid < off) red[tid] += red[tid + off];
        __syncthreads();
    }
    if (tid == 0) {
        float m = losssum[0] * (1.0f / 8388608.0f);
        out[LOSS_OFF] = m + 0.25f * m;
        out[PERP_OFF] = expf(-red[0]);
    }
}

extern "C" void kernel_launch(void* const* d_in, const int* in_sizes, int n_in,
                              void* d_out, int out_size, void* d_ws, size_t ws_size,
                              hipStream_t stream) {
    const float* z = (const float*)d_in[0];
    const float* emb = (const float*)d_in[1];
    float* out = (float*)d_out;
    unsigned short* ehsw = (unsigned short*)d_ws;            // 1024*256 ushort (swizzled)
    unsigned short* elsw = ehsw + (size_t)KCODE * CDIM;      // 1024*256 ushort
    float* enorm = (float*)(elsw + (size_t)KCODE * CDIM);    // 1024 f
    float* counts = enorm + KCODE;                           // 1024 f
    float* losssum = counts + KCODE;                         // 1 f

    vq_prep<<<256, 256, 0, stream>>>(emb, ehsw, elsw, enorm, counts, losssum);
    vq_main<<<256, 512, 0, stream>>>(z, emb, ehsw, elsw, enorm, counts, losssum, out);
    vq_finalize<<<1, 256, 0, stream>>>(counts, losssum, out);
}